// Round 1
// baseline (638.737 us; speedup 1.0000x reference)
//
#include <hip/hip_runtime.h>
#include <hip/hip_bf16.h>
#include <math.h>

#define B_SZ 32
#define T_SZ 2048
#define H_SZ 1024
#define U_SZ 1024

#define BM 64
#define BN 256
#define BK 64
#define UT_N (U_SZ / BN)   // 4

typedef __attribute__((ext_vector_type(8))) short bf16x8;   // 8 bf16 = 4 VGPRs
typedef __attribute__((ext_vector_type(4))) float f32x4;    // mfma 16x16 accumulator

// fp32 -> bf16 round-to-nearest-even
__device__ __forceinline__ unsigned int f2bf(float f) {
  union { float f; unsigned int u; } x; x.f = f;
  unsigned int r = x.u + 0x7FFFu + ((x.u >> 16) & 1u);
  return r >> 16;
}

__device__ __forceinline__ float bf2f(unsigned int lo16) {
  union { unsigned int u; float f; } x; x.u = lo16 << 16; return x.f;
}

// async global -> LDS, 16 B per lane. LDS dest = wave-uniform base + lane*16.
__device__ __forceinline__ void async_cp16(const unsigned short* g, unsigned short* l) {
  __builtin_amdgcn_global_load_lds(
      (const __attribute__((address_space(1))) unsigned int*)g,
      (__attribute__((address_space(3))) unsigned int*)l, 16, 0, 0);
}

__device__ __forceinline__ float fast_tanh(float x) {
  const float e = __expf(x + x);
  return (e - 1.0f) * __builtin_amdgcn_rcpf(e + 1.0f);
}

// ---------------------------------------------------------------------------
// Fused prep: [0,cvtN): enc fp32->bf16 | [cvtN,+256): W2->W2t | [+256,+768): qq
// One dispatch instead of three (launch-gap + overlap of BW-bound cvt with
// latency-bound qq).
// ---------------------------------------------------------------------------
__global__ __launch_bounds__(256) void k_prep(
    const float* __restrict__ enc, unsigned short* __restrict__ encb,
    const float* __restrict__ W2, unsigned short* __restrict__ W2t,
    const float* __restrict__ dec, const float* __restrict__ W1,
    const float* __restrict__ b1, const float* __restrict__ b2,
    float* __restrict__ qq, int cvtN)
{
  __shared__ char lds_raw[64 * 65 * 2];   // 8320 B, reused per branch
  const int bid = blockIdx.x;
  const int tid = threadIdx.x;

  if (bid < cvtN) {
    // ---- enc fp32 -> bf16, 8 elems/thread ----
    const size_t i = ((size_t)bid * 256 + tid) * 8;
    const float4 a = *(const float4*)(enc + i);
    const float4 b = *(const float4*)(enc + i + 4);
    uint4 o;
    o.x = f2bf(a.x) | (f2bf(a.y) << 16);
    o.y = f2bf(a.z) | (f2bf(a.w) << 16);
    o.z = f2bf(b.x) | (f2bf(b.y) << 16);
    o.w = f2bf(b.z) | (f2bf(b.w) << 16);
    *(uint4*)(encb + i) = o;
  } else if (bid < cvtN + 256) {
    // ---- W2 [H][U] -> W2t [U][H] bf16 ----
    unsigned short (*tile)[65] = (unsigned short(*)[65])lds_raw;
    const int idx = bid - cvtN;
    const int bu = idx & 15, bh = idx >> 4;
    const int tc = tid & 63, tr = tid >> 6;
    #pragma unroll
    for (int i = 0; i < 16; ++i) {
      const int hl = tr + i * 4;
      tile[tc][hl] = (unsigned short)f2bf(W2[(size_t)(bh * 64 + hl) * U_SZ + bu * 64 + tc]);
    }
    __syncthreads();
    #pragma unroll
    for (int i = 0; i < 16; ++i) {
      const int ul = tr + i * 4;
      W2t[(size_t)(bu * 64 + ul) * H_SZ + bh * 64 + tc] = tile[ul][tc];
    }
  } else {
    // ---- qq[b][u] = dec[b]·W1[:,u] + b1[u] + b2[u] ----
    float (*red)[64] = (float(*)[64])lds_raw;
    const int idx = bid - (cvtN + 256);    // 0..511
    const int ul = tid & 63;
    const int hq = tid >> 6;
    const int u  = (idx & 15) * 64 + ul;
    const int b  = idx >> 4;
    const float* dh = dec + b * H_SZ + hq * 256;
    const float* w  = W1 + (size_t)(hq * 256) * U_SZ + u;
    float acc = 0.0f;
    #pragma unroll 8
    for (int h = 0; h < 256; ++h) acc += dh[h] * w[(size_t)h * U_SZ];
    red[hq][ul] = acc;
    __syncthreads();
    if (tid < 64) {
      const float s = red[0][ul] + red[1][ul] + red[2][ul] + red[3][ul];
      qq[b * U_SZ + u] = s + b1[u] + b2[u];
    }
  }
}

// ---------------------------------------------------------------------------
// Fused GEMM + tanh·V reduce: score[m] = sum_u tanh((enc@W2)[m][u] + qq) * V[u]
// BM=64 rows/block, ut-loop over 4 BN=256 col tiles, BK=64. Grid 1024 blocks
// (4/CU by grid; 3/CU by LDS=40.5 KB) — occupancy fix vs round 2's 512.
// 4 waves: each computes all 64 rows x its 64-col slice (4x4 16x16x32 mfma).
// LDS swizzle (per round 2, measured 0 conflicts): row stride 128 B, 8x16 B
// chunks, stored chunk' = (chunk + row) & 7; staged via global_load_lds(16B)
// with the rotation applied on the global-address side.
// ---------------------------------------------------------------------------
template <bool PRE_BF16>
__global__ __launch_bounds__(256) void k_gemm_score(
    const unsigned short* __restrict__ encb,   // bf16 enc (fast path)
    const float* __restrict__ encf,            // fp32 enc (fallback path)
    const unsigned short* __restrict__ W2t,
    const float* __restrict__ qq, const float* __restrict__ Vv,
    float* __restrict__ score)
{
  __shared__ unsigned short Al[BM * BK];   // 8 KB
  __shared__ unsigned short Bl[BN * BK];   // 32 KB
  __shared__ float scoreS[BM];

  const int tid  = threadIdx.x;
  const int wave = tid >> 6;
  const int lane = tid & 63;
  const int quad = lane >> 4;
  const int l16  = lane & 15;
  const int m0   = blockIdx.x * BM;
  const int b    = m0 >> 11;       // 64 rows share one batch (2048 % 64 == 0)

  if (tid < BM) scoreS[tid] = 0.0f;

  // A staging: 512 slots of 16 B = 2 wave-insts per wave
  size_t aoff[2]; unsigned short* dstA[2];
  #pragma unroll
  for (int i = 0; i < 2; ++i) {
    const int slot = (i * 4 + wave) * 64 + lane;
    const int r = slot >> 3;                 // 0..63
    const int c = ((slot & 7) - r) & 7;      // source chunk (swizzle)
    aoff[i] = (size_t)(m0 + r) * H_SZ + c * 8;
    dstA[i] = &Al[(i * 4 + wave) * 512];
  }
  // B staging: 2048 slots = 8 wave-insts per wave
  size_t boff[8]; unsigned short* dstB[8];
  #pragma unroll
  for (int i = 0; i < 8; ++i) {
    const int slot = (i * 4 + wave) * 64 + lane;
    const int r = slot >> 3;                 // 0..255 (u_local)
    const int c = ((slot & 7) - r) & 7;
    boff[i] = (size_t)r * H_SZ + c * 8;
    dstB[i] = &Bl[(i * 4 + wave) * 512];
  }

  const int ar[4] = { 0 * 16 + l16, 1 * 16 + l16, 2 * 16 + l16, 3 * 16 + l16 };
  const int bu[4] = { wave * 64 + 0 * 16 + l16, wave * 64 + 1 * 16 + l16,
                      wave * 64 + 2 * 16 + l16, wave * 64 + 3 * 16 + l16 };

  for (int ut = 0; ut < UT_N; ++ut) {
    const int u0 = ut * BN;
    f32x4 acc[4][4];
    #pragma unroll
    for (int rt = 0; rt < 4; ++rt)
      #pragma unroll
      for (int ct = 0; ct < 4; ++ct)
        #pragma unroll
        for (int r = 0; r < 4; ++r) acc[rt][ct][r] = 0.0f;

    for (int kk = 0; kk < H_SZ; kk += BK) {
      __syncthreads();
      if constexpr (PRE_BF16) {
        #pragma unroll
        for (int i = 0; i < 2; ++i) async_cp16(encb + aoff[i] + kk, dstA[i]);
      } else {
        #pragma unroll
        for (int i = 0; i < 2; ++i) {
          const int slot = i * 256 + tid;
          const int r = slot >> 3;
          const int c = ((slot & 7) - r) & 7;
          const float* src = encf + (size_t)(m0 + r) * H_SZ + kk + c * 8;
          const float4 x = *(const float4*)src;
          const float4 y = *(const float4*)(src + 4);
          uint4 o;
          o.x = f2bf(x.x) | (f2bf(x.y) << 16);
          o.y = f2bf(x.z) | (f2bf(x.w) << 16);
          o.z = f2bf(y.x) | (f2bf(y.y) << 16);
          o.w = f2bf(y.z) | (f2bf(y.w) << 16);
          *(uint4*)&Al[slot * 8] = o;
        }
      }
      #pragma unroll
      for (int i = 0; i < 8; ++i)
        async_cp16(W2t + (size_t)u0 * H_SZ + boff[i] + kk, dstB[i]);
      __syncthreads();

      #pragma unroll
      for (int h = 0; h < 2; ++h) {
        bf16x8 af[4], bfr[4];
        #pragma unroll
        for (int rt = 0; rt < 4; ++rt)
          af[rt] = *(const bf16x8*)&Al[ar[rt] * 64 + ((h * 4 + quad + ar[rt]) & 7) * 8];
        #pragma unroll
        for (int ct = 0; ct < 4; ++ct)
          bfr[ct] = *(const bf16x8*)&Bl[bu[ct] * 64 + ((h * 4 + quad + bu[ct]) & 7) * 8];
        #pragma unroll
        for (int rt = 0; rt < 4; ++rt)
          #pragma unroll
          for (int ct = 0; ct < 4; ++ct)
            acc[rt][ct] = __builtin_amdgcn_mfma_f32_16x16x32_bf16(
                af[rt], bfr[ct], acc[rt][ct], 0, 0, 0);
      }
    }

    // fused epilogue: C/D layout col=l16(+16ct), row=quad*4+r(+16rt)
    float part[4][4];
    #pragma unroll
    for (int rt = 0; rt < 4; ++rt)
      #pragma unroll
      for (int r = 0; r < 4; ++r) part[rt][r] = 0.0f;
    #pragma unroll
    for (int ct = 0; ct < 4; ++ct) {
      const int u = u0 + wave * 64 + ct * 16 + l16;
      const float qv = qq[b * U_SZ + u];
      const float vv = Vv[u];
      #pragma unroll
      for (int rt = 0; rt < 4; ++rt)
        #pragma unroll
        for (int r = 0; r < 4; ++r)
          part[rt][r] += fast_tanh(acc[rt][ct][r] + qv) * vv;
    }
    #pragma unroll
    for (int rt = 0; rt < 4; ++rt)
      #pragma unroll
      for (int r = 0; r < 4; ++r) {
        float p = part[rt][r];
        p += __shfl_xor(p, 1);
        p += __shfl_xor(p, 2);
        p += __shfl_xor(p, 4);
        p += __shfl_xor(p, 8);
        part[rt][r] = p;
      }
    if (l16 == 0) {
      #pragma unroll
      for (int rt = 0; rt < 4; ++rt)
        #pragma unroll
        for (int r = 0; r < 4; ++r)
          atomicAdd(&scoreS[rt * 16 + quad * 4 + r], part[rt][r]);
    }
  }
  __syncthreads();
  if (tid < BM) score[m0 + tid] = scoreS[tid];
}

// ---------------------------------------------------------------------------
// softmax over T per batch (bv dropped: constant shift, softmax-invariant)
// ---------------------------------------------------------------------------
__global__ void k_softmax(const float* __restrict__ score, float* __restrict__ attn) {
  const int b = blockIdx.x;
  const int tid = threadIdx.x;   // 256
  __shared__ float wmax[4], wsum[4];
  const float* s = score + b * T_SZ;
  float v[8];
  float lmax = -INFINITY;
  #pragma unroll
  for (int i = 0; i < 8; ++i) { v[i] = s[tid + i * 256]; lmax = fmaxf(lmax, v[i]); }
  #pragma unroll
  for (int m = 1; m <= 32; m <<= 1) lmax = fmaxf(lmax, __shfl_xor(lmax, m));
  if ((tid & 63) == 0) wmax[tid >> 6] = lmax;
  __syncthreads();
  const float gmax = fmaxf(fmaxf(wmax[0], wmax[1]), fmaxf(wmax[2], wmax[3]));
  float lsum = 0.0f;
  #pragma unroll
  for (int i = 0; i < 8; ++i) { v[i] = __expf(v[i] - gmax); lsum += v[i]; }
  #pragma unroll
  for (int m = 1; m <= 32; m <<= 1) lsum += __shfl_xor(lsum, m);
  if ((tid & 63) == 0) wsum[tid >> 6] = lsum;
  __syncthreads();
  const float inv = 1.0f / (wsum[0] + wsum[1] + wsum[2] + wsum[3]);
  #pragma unroll
  for (int i = 0; i < 8; ++i) attn[b * T_SZ + tid + i * 256] = v[i] * inv;
}

// ---------------------------------------------------------------------------
// context[b][h] = sum_t attn[b][t] * enc[b][t][h] — bf16 enc, 2 h per thread
// ---------------------------------------------------------------------------
__global__ void k_context_bf16(const unsigned short* __restrict__ encb,
                               const float* __restrict__ attn, float* __restrict__ ctx) {
  const int tcx = blockIdx.x;   // 0..7
  const int hc  = blockIdx.y;   // 0..1
  const int b   = blockIdx.z;   // 0..31
  const int h0  = hc * 512 + threadIdx.x * 2;
  const unsigned short* e = encb + ((size_t)b * T_SZ + tcx * 256) * H_SZ + h0;
  const float* a = attn + b * T_SZ + tcx * 256;
  float c0 = 0, c1 = 0;
  #pragma unroll 4
  for (int t = 0; t < 256; ++t) {
    const unsigned int v = *(const unsigned int*)&e[(size_t)t * H_SZ];
    c0 += a[t] * bf2f(v & 0xFFFFu);
    c1 += a[t] * bf2f(v >> 16);
  }
  atomicAdd(&ctx[b * H_SZ + h0],     c0);
  atomicAdd(&ctx[b * H_SZ + h0 + 1], c1);
}

__global__ void k_context_f32(const float* __restrict__ enc,
                              const float* __restrict__ attn, float* __restrict__ ctx) {
  const int tcx = blockIdx.x, hc = blockIdx.y, b = blockIdx.z;
  const int h = hc * 256 + threadIdx.x;
  const float* e = enc + ((size_t)b * T_SZ + tcx * 256) * H_SZ + h;
  const float* a = attn + b * T_SZ + tcx * 256;
  float a0 = 0, a1 = 0, a2 = 0, a3 = 0;
  for (int t = 0; t < 256; t += 4) {
    a0 += a[t]     * e[(size_t)t * H_SZ];
    a1 += a[t + 1] * e[(size_t)(t + 1) * H_SZ];
    a2 += a[t + 2] * e[(size_t)(t + 2) * H_SZ];
    a3 += a[t + 3] * e[(size_t)(t + 3) * H_SZ];
  }
  atomicAdd(&ctx[b * H_SZ + h], (a0 + a1) + (a2 + a3));
}

// ---------------------------------------------------------------------------
extern "C" void kernel_launch(void* const* d_in, const int* in_sizes, int n_in,
                              void* d_out, int out_size, void* d_ws, size_t ws_size,
                              hipStream_t stream) {
  const float* dec = (const float*)d_in[0];
  const float* enc = (const float*)d_in[1];
  const float* W1  = (const float*)d_in[2];
  const float* b1  = (const float*)d_in[3];
  const float* W2  = (const float*)d_in[4];
  const float* b2  = (const float*)d_in[5];
  const float* Vv  = (const float*)d_in[6];
  // d_in[7] = bv: constant shift inside softmax -> no effect on outputs.

  const size_t encb_bytes = (size_t)B_SZ * T_SZ * H_SZ * 2;   // 128 MB
  const size_t fast_need  = encb_bytes + (2u << 20) + (128u << 10) + (256u << 10);
  const bool fast = ws_size >= fast_need;

  char* ws = (char*)d_ws;
  unsigned short* encb = nullptr;
  unsigned short* W2t;
  float *qq, *score;
  if (fast) {
    encb  = (unsigned short*)ws;
    W2t   = (unsigned short*)(ws + encb_bytes);
    qq    = (float*)(ws + encb_bytes + (2u << 20));
    score = (float*)(ws + encb_bytes + (2u << 20) + (128u << 10));
  } else {
    W2t   = (unsigned short*)ws;
    qq    = (float*)(ws + (2u << 20));
    score = (float*)(ws + (2u << 20) + (128u << 10));
  }

  float* ctx  = (float*)d_out;                  // [32,1024]
  float* attn = (float*)d_out + B_SZ * H_SZ;    // [32,2048,1]

  hipMemsetAsync(ctx, 0, B_SZ * H_SZ * sizeof(float), stream);
  const int cvtN = fast ? (B_SZ * T_SZ * H_SZ) / (256 * 8) : 0;   // 2048 or 0
  k_prep<<<cvtN + 256 + 512, 256, 0, stream>>>(enc, encb, W2, W2t,
                                               dec, W1, b1, b2, qq, cvtN);
  if (fast)
    k_gemm_score<true><<<(B_SZ * T_SZ) / BM, 256, 0, stream>>>(encb, enc, W2t, qq, Vv, score);
  else
    k_gemm_score<false><<<(B_SZ * T_SZ) / BM, 256, 0, stream>>>(encb, enc, W2t, qq, Vv, score);
  k_softmax<<<32, 256, 0, stream>>>(score, attn);
  if (fast)
    k_context_bf16<<<dim3(8, 2, 32), 256, 0, stream>>>(encb, attn, ctx);
  else
    k_context_f32<<<dim3(8, 4, 32), 256, 0, stream>>>(enc, attn, ctx);
}

// Round 2
// 599.360 us; speedup vs baseline: 1.0657x; 1.0657x over previous
//
#include <hip/hip_runtime.h>
#include <hip/hip_bf16.h>
#include <math.h>

#define B_SZ 32
#define T_SZ 2048
#define H_SZ 1024
#define U_SZ 1024

#define BM 64
#define BN 256
#define BK 64
#define UT_N (U_SZ / BN)   // 4
#define BM2 256            // new big-tile GEMM row-block

typedef __attribute__((ext_vector_type(8))) short bf16x8;   // 8 bf16 = 4 VGPRs
typedef __attribute__((ext_vector_type(4))) float f32x4;    // mfma 16x16 accumulator

// fp32 -> bf16 round-to-nearest-even
__device__ __forceinline__ unsigned int f2bf(float f) {
  union { float f; unsigned int u; } x; x.f = f;
  unsigned int r = x.u + 0x7FFFu + ((x.u >> 16) & 1u);
  return r >> 16;
}

__device__ __forceinline__ float bf2f(unsigned int lo16) {
  union { unsigned int u; float f; } x; x.u = lo16 << 16; return x.f;
}

// async global -> LDS, 16 B per lane. LDS dest = wave-uniform base + lane*16.
__device__ __forceinline__ void async_cp16(const unsigned short* g, unsigned short* l) {
  __builtin_amdgcn_global_load_lds(
      (const __attribute__((address_space(1))) unsigned int*)g,
      (__attribute__((address_space(3))) unsigned int*)l, 16, 0, 0);
}

__device__ __forceinline__ float fast_tanh(float x) {
  const float e = __expf(x + x);
  return (e - 1.0f) * __builtin_amdgcn_rcpf(e + 1.0f);
}

// ---------------------------------------------------------------------------
// Fused prep: [0,cvtN): enc fp32->bf16 | [cvtN,+256): W2->W2t | [+256,+768): qq
// ---------------------------------------------------------------------------
__global__ __launch_bounds__(256) void k_prep(
    const float* __restrict__ enc, unsigned short* __restrict__ encb,
    const float* __restrict__ W2, unsigned short* __restrict__ W2t,
    const float* __restrict__ dec, const float* __restrict__ W1,
    const float* __restrict__ b1, const float* __restrict__ b2,
    float* __restrict__ qq, int cvtN)
{
  __shared__ char lds_raw[64 * 65 * 2];   // 8320 B, reused per branch
  const int bid = blockIdx.x;
  const int tid = threadIdx.x;

  if (bid < cvtN) {
    const size_t i = ((size_t)bid * 256 + tid) * 8;
    const float4 a = *(const float4*)(enc + i);
    const float4 b = *(const float4*)(enc + i + 4);
    uint4 o;
    o.x = f2bf(a.x) | (f2bf(a.y) << 16);
    o.y = f2bf(a.z) | (f2bf(a.w) << 16);
    o.z = f2bf(b.x) | (f2bf(b.y) << 16);
    o.w = f2bf(b.z) | (f2bf(b.w) << 16);
    *(uint4*)(encb + i) = o;
  } else if (bid < cvtN + 256) {
    unsigned short (*tile)[65] = (unsigned short(*)[65])lds_raw;
    const int idx = bid - cvtN;
    const int bu = idx & 15, bh = idx >> 4;
    const int tc = tid & 63, tr = tid >> 6;
    #pragma unroll
    for (int i = 0; i < 16; ++i) {
      const int hl = tr + i * 4;
      tile[tc][hl] = (unsigned short)f2bf(W2[(size_t)(bh * 64 + hl) * U_SZ + bu * 64 + tc]);
    }
    __syncthreads();
    #pragma unroll
    for (int i = 0; i < 16; ++i) {
      const int ul = tr + i * 4;
      W2t[(size_t)(bu * 64 + ul) * H_SZ + bh * 64 + tc] = tile[ul][tc];
    }
  } else {
    float (*red)[64] = (float(*)[64])lds_raw;
    const int idx = bid - (cvtN + 256);    // 0..511
    const int ul = tid & 63;
    const int hq = tid >> 6;
    const int u  = (idx & 15) * 64 + ul;
    const int b  = idx >> 4;
    const float* dh = dec + b * H_SZ + hq * 256;
    const float* w  = W1 + (size_t)(hq * 256) * U_SZ + u;
    float acc = 0.0f;
    #pragma unroll 8
    for (int h = 0; h < 256; ++h) acc += dh[h] * w[(size_t)h * U_SZ];
    red[hq][ul] = acc;
    __syncthreads();
    if (tid < 64) {
      const float s = red[0][ul] + red[1][ul] + red[2][ul] + red[3][ul];
      qq[b * U_SZ + u] = s + b1[u] + b2[u];
    }
  }
}

// ---------------------------------------------------------------------------
// NEW fast-path fused GEMM + tanh·V reduce.
// BM2=256 rows/block, 8 waves (2M x 4N), wave subtile 128x64, BK=64.
// 64 global K-steps (ut-major: 4 ut x 16 kk) run as ONE counted-vmcnt
// 2-deep pipeline: each wave issues exactly 8 global_load_lds per tile,
// waits vmcnt(8) (never 0 in-loop), raw s_barrier. LDS 128 KB double-buffer.
// Swizzle identical to verified baseline: chunk' = (chunk + row) & 7.
// ---------------------------------------------------------------------------
__global__ __launch_bounds__(512, 2) void k_gemm_score2(
    const unsigned short* __restrict__ encb,
    const unsigned short* __restrict__ W2t,
    const float* __restrict__ qq, const float* __restrict__ Vv,
    float* __restrict__ score)
{
  __shared__ unsigned short Al[2][BM2 * BK];   // 64 KB
  __shared__ unsigned short Bl[2][BN * BK];    // 64 KB

  const int tid  = threadIdx.x;
  const int wid  = tid >> 6;      // 0..7
  const int lane = tid & 63;
  const int quad = lane >> 4;
  const int l16  = lane & 15;
  const int wr   = wid >> 2;      // 0..1  (M side)
  const int wc   = wid & 3;       // 0..3  (N side)
  const int m0   = blockIdx.x * BM2;
  const int b    = m0 >> 11;      // 256 rows within one batch (2048 % 256 == 0)

  // staging address precompute: 4 A-slots + 4 B-slots per wave, 16 B each lane
  unsigned int aoff[4], boff[4];
  int swi[4];
  #pragma unroll
  for (int j = 0; j < 4; ++j) {
    const int sw = j * 8 + wid;          // wave-inst slot 0..31
    const int s  = sw * 64 + lane;       // 16B slot 0..2047
    const int r  = s >> 3;               // row 0..255
    const int c  = ((s & 7) - r) & 7;    // source chunk (swizzle)
    aoff[j] = (unsigned int)((m0 + r) * H_SZ + c * 8);
    boff[j] = (unsigned int)(r * H_SZ + c * 8);
    swi[j]  = sw * 512;                  // LDS ushort offset of this wave-inst
  }

  f32x4 acc[8][4];
  float part[8][4];
  #pragma unroll
  for (int rt = 0; rt < 8; ++rt)
    #pragma unroll
    for (int ct = 0; ct < 4; ++ct) {
      part[rt][ct] = 0.0f;
      #pragma unroll
      for (int r = 0; r < 4; ++r) acc[rt][ct][r] = 0.0f;
    }

  auto STAGE = [&](int i) {
    const int ut = i >> 4;
    const unsigned int kk = (unsigned int)(i & 15) * 64u;
    const int bs = i & 1;
    #pragma unroll
    for (int j = 0; j < 4; ++j)
      async_cp16(encb + aoff[j] + kk, &Al[bs][swi[j]]);
    const unsigned int uoff = (unsigned int)(ut * 256) * H_SZ + kk;
    #pragma unroll
    for (int j = 0; j < 4; ++j)
      async_cp16(W2t + uoff + boff[j], &Bl[bs][swi[j]]);
  };

  auto COMPUTE = [&](int i) {
    const unsigned short* Ab = Al[i & 1];
    const unsigned short* Bb = Bl[i & 1];
    #pragma unroll
    for (int h = 0; h < 2; ++h) {
      bf16x8 af[8], bfr[4];
      #pragma unroll
      for (int rt = 0; rt < 8; ++rt) {
        const int ar = wr * 128 + rt * 16 + l16;
        af[rt] = *(const bf16x8*)&Ab[ar * 64 + ((h * 4 + quad + ar) & 7) * 8];
      }
      #pragma unroll
      for (int ct = 0; ct < 4; ++ct) {
        const int bu = wc * 64 + ct * 16 + l16;
        bfr[ct] = *(const bf16x8*)&Bb[bu * 64 + ((h * 4 + quad + bu) & 7) * 8];
      }
      #pragma unroll
      for (int rt = 0; rt < 8; ++rt)
        #pragma unroll
        for (int ct = 0; ct < 4; ++ct)
          acc[rt][ct] = __builtin_amdgcn_mfma_f32_16x16x32_bf16(
              af[rt], bfr[ct], acc[rt][ct], 0, 0, 0);
    }
  };

  auto EPILOGUE = [&](int ut) {
    #pragma unroll
    for (int ct = 0; ct < 4; ++ct) {
      const int u = ut * 256 + wc * 64 + ct * 16 + l16;
      const float qv = qq[b * U_SZ + u];
      const float vv = Vv[u];
      #pragma unroll
      for (int rt = 0; rt < 8; ++rt)
        #pragma unroll
        for (int r = 0; r < 4; ++r)
          part[rt][r] += fast_tanh(acc[rt][ct][r] + qv) * vv;
    }
    #pragma unroll
    for (int rt = 0; rt < 8; ++rt)
      #pragma unroll
      for (int ct = 0; ct < 4; ++ct)
        #pragma unroll
        for (int r = 0; r < 4; ++r) acc[rt][ct][r] = 0.0f;
  };

  STAGE(0);
  for (int i = 0; i < 63; ++i) {
    STAGE(i + 1);
    asm volatile("s_waitcnt vmcnt(8)" ::: "memory");
    __builtin_amdgcn_s_barrier();
    __builtin_amdgcn_sched_barrier(0);
    COMPUTE(i);
    if ((i & 15) == 15) EPILOGUE(i >> 4);
    __builtin_amdgcn_sched_barrier(0);
    __builtin_amdgcn_s_barrier();
  }
  asm volatile("s_waitcnt vmcnt(0)" ::: "memory");
  __builtin_amdgcn_s_barrier();
  __builtin_amdgcn_sched_barrier(0);
  COMPUTE(63);
  EPILOGUE(3);

  // cross-wave score reduce: overlay scoreS on freed Al
  __syncthreads();
  float* scoreS = (float*)&Al[0][0];
  if (tid < BM2) scoreS[tid] = 0.0f;
  __syncthreads();
  #pragma unroll
  for (int rt = 0; rt < 8; ++rt)
    #pragma unroll
    for (int r = 0; r < 4; ++r) {
      float p = part[rt][r];
      p += __shfl_xor(p, 1);
      p += __shfl_xor(p, 2);
      p += __shfl_xor(p, 4);
      p += __shfl_xor(p, 8);
      if (l16 == 0) atomicAdd(&scoreS[wr * 128 + rt * 16 + quad * 4 + r], p);
    }
  __syncthreads();
  if (tid < BM2) score[m0 + tid] = scoreS[tid];
}

// ---------------------------------------------------------------------------
// OLD GEMM kept as the no-workspace fallback path (fp32 in-kernel convert).
// ---------------------------------------------------------------------------
__global__ __launch_bounds__(256) void k_gemm_score_f32(
    const float* __restrict__ encf,
    const unsigned short* __restrict__ W2t,
    const float* __restrict__ qq, const float* __restrict__ Vv,
    float* __restrict__ score)
{
  __shared__ unsigned short Alo[BM * BK];   // 8 KB
  __shared__ unsigned short Blo[BN * BK];   // 32 KB
  __shared__ float scoreS[BM];

  const int tid  = threadIdx.x;
  const int wave = tid >> 6;
  const int lane = tid & 63;
  const int quad = lane >> 4;
  const int l16  = lane & 15;
  const int m0   = blockIdx.x * BM;
  const int b    = m0 >> 11;

  if (tid < BM) scoreS[tid] = 0.0f;

  size_t boff[8]; unsigned short* dstB[8];
  #pragma unroll
  for (int i = 0; i < 8; ++i) {
    const int slot = (i * 4 + wave) * 64 + lane;
    const int r = slot >> 3;
    const int c = ((slot & 7) - r) & 7;
    boff[i] = (size_t)r * H_SZ + c * 8;
    dstB[i] = &Blo[(i * 4 + wave) * 512];
  }

  const int ar[4] = { 0 * 16 + l16, 1 * 16 + l16, 2 * 16 + l16, 3 * 16 + l16 };
  const int bu[4] = { wave * 64 + 0 * 16 + l16, wave * 64 + 1 * 16 + l16,
                      wave * 64 + 2 * 16 + l16, wave * 64 + 3 * 16 + l16 };

  for (int ut = 0; ut < UT_N; ++ut) {
    const int u0 = ut * BN;
    f32x4 acc[4][4];
    #pragma unroll
    for (int rt = 0; rt < 4; ++rt)
      #pragma unroll
      for (int ct = 0; ct < 4; ++ct)
        #pragma unroll
        for (int r = 0; r < 4; ++r) acc[rt][ct][r] = 0.0f;

    for (int kk = 0; kk < H_SZ; kk += BK) {
      __syncthreads();
      #pragma unroll
      for (int i = 0; i < 2; ++i) {
        const int slot = i * 256 + tid;
        const int r = slot >> 3;
        const int c = ((slot & 7) - r) & 7;
        const float* src = encf + (size_t)(m0 + r) * H_SZ + kk + c * 8;
        const float4 x = *(const float4*)src;
        const float4 y = *(const float4*)(src + 4);
        uint4 o;
        o.x = f2bf(x.x) | (f2bf(x.y) << 16);
        o.y = f2bf(x.z) | (f2bf(x.w) << 16);
        o.z = f2bf(y.x) | (f2bf(y.y) << 16);
        o.w = f2bf(y.z) | (f2bf(y.w) << 16);
        *(uint4*)&Alo[slot * 8] = o;
      }
      #pragma unroll
      for (int i = 0; i < 8; ++i)
        async_cp16(W2t + (size_t)u0 * H_SZ + boff[i] + kk, dstB[i]);
      __syncthreads();

      #pragma unroll
      for (int h = 0; h < 2; ++h) {
        bf16x8 af[4], bfr[4];
        #pragma unroll
        for (int rt = 0; rt < 4; ++rt)
          af[rt] = *(const bf16x8*)&Alo[ar[rt] * 64 + ((h * 4 + quad + ar[rt]) & 7) * 8];
        #pragma unroll
        for (int ct = 0; ct < 4; ++ct)
          bfr[ct] = *(const bf16x8*)&Blo[bu[ct] * 64 + ((h * 4 + quad + bu[ct]) & 7) * 8];
        #pragma unroll
        for (int rt = 0; rt < 4; ++rt)
          #pragma unroll
          for (int ct = 0; ct < 4; ++ct)
            acc[rt][ct] = __builtin_amdgcn_mfma_f32_16x16x32_bf16(
                af[rt], bfr[ct], acc[rt][ct], 0, 0, 0);
      }
    }

    float part[4][4];
    #pragma unroll
    for (int rt = 0; rt < 4; ++rt)
      #pragma unroll
      for (int r = 0; r < 4; ++r) part[rt][r] = 0.0f;
    #pragma unroll
    for (int ct = 0; ct < 4; ++ct) {
      const int u = u0 + wave * 64 + ct * 16 + l16;
      const float qv = qq[b * U_SZ + u];
      const float vv = Vv[u];
      #pragma unroll
      for (int rt = 0; rt < 4; ++rt)
        #pragma unroll
        for (int r = 0; r < 4; ++r)
          part[rt][r] += fast_tanh(acc[rt][ct][r] + qv) * vv;
    }
    #pragma unroll
    for (int rt = 0; rt < 4; ++rt)
      #pragma unroll
      for (int r = 0; r < 4; ++r) {
        float p = part[rt][r];
        p += __shfl_xor(p, 1);
        p += __shfl_xor(p, 2);
        p += __shfl_xor(p, 4);
        p += __shfl_xor(p, 8);
        part[rt][r] = p;
      }
    if (l16 == 0) {
      #pragma unroll
      for (int rt = 0; rt < 4; ++rt)
        #pragma unroll
        for (int r = 0; r < 4; ++r)
          atomicAdd(&scoreS[rt * 16 + quad * 4 + r], part[rt][r]);
    }
  }
  __syncthreads();
  if (tid < BM) score[m0 + tid] = scoreS[tid];
}

// ---------------------------------------------------------------------------
// softmax over T per batch (bv dropped: constant shift, softmax-invariant)
// ---------------------------------------------------------------------------
__global__ void k_softmax(const float* __restrict__ score, float* __restrict__ attn) {
  const int b = blockIdx.x;
  const int tid = threadIdx.x;   // 256
  __shared__ float wmax[4], wsum[4];
  const float* s = score + b * T_SZ;
  float v[8];
  float lmax = -INFINITY;
  #pragma unroll
  for (int i = 0; i < 8; ++i) { v[i] = s[tid + i * 256]; lmax = fmaxf(lmax, v[i]); }
  #pragma unroll
  for (int m = 1; m <= 32; m <<= 1) lmax = fmaxf(lmax, __shfl_xor(lmax, m));
  if ((tid & 63) == 0) wmax[tid >> 6] = lmax;
  __syncthreads();
  const float gmax = fmaxf(fmaxf(wmax[0], wmax[1]), fmaxf(wmax[2], wmax[3]));
  float lsum = 0.0f;
  #pragma unroll
  for (int i = 0; i < 8; ++i) { v[i] = __expf(v[i] - gmax); lsum += v[i]; }
  #pragma unroll
  for (int m = 1; m <= 32; m <<= 1) lsum += __shfl_xor(lsum, m);
  if ((tid & 63) == 0) wsum[tid >> 6] = lsum;
  __syncthreads();
  const float inv = 1.0f / (wsum[0] + wsum[1] + wsum[2] + wsum[3]);
  #pragma unroll
  for (int i = 0; i < 8; ++i) attn[b * T_SZ + tid + i * 256] = v[i] * inv;
}

// ---------------------------------------------------------------------------
// context[b][h] = sum_t attn[b][t] * enc[b][t][h] — bf16 enc, 2 h per thread
// ---------------------------------------------------------------------------
__global__ void k_context_bf16(const unsigned short* __restrict__ encb,
                               const float* __restrict__ attn, float* __restrict__ ctx) {
  const int tcx = blockIdx.x;   // 0..7
  const int hc  = blockIdx.y;   // 0..1
  const int b   = blockIdx.z;   // 0..31
  const int h0  = hc * 512 + threadIdx.x * 2;
  const unsigned short* e = encb + ((size_t)b * T_SZ + tcx * 256) * H_SZ + h0;
  const float* a = attn + b * T_SZ + tcx * 256;
  float c0 = 0, c1 = 0;
  #pragma unroll 4
  for (int t = 0; t < 256; ++t) {
    const unsigned int v = *(const unsigned int*)&e[(size_t)t * H_SZ];
    c0 += a[t] * bf2f(v & 0xFFFFu);
    c1 += a[t] * bf2f(v >> 16);
  }
  atomicAdd(&ctx[b * H_SZ + h0],     c0);
  atomicAdd(&ctx[b * H_SZ + h0 + 1], c1);
}

__global__ void k_context_f32(const float* __restrict__ enc,
                              const float* __restrict__ attn, float* __restrict__ ctx) {
  const int tcx = blockIdx.x, hc = blockIdx.y, b = blockIdx.z;
  const int h = hc * 256 + threadIdx.x;
  const float* e = enc + ((size_t)b * T_SZ + tcx * 256) * H_SZ + h;
  const float* a = attn + b * T_SZ + tcx * 256;
  float a0 = 0, a1 = 0, a2 = 0, a3 = 0;
  for (int t = 0; t < 256; t += 4) {
    a0 += a[t]     * e[(size_t)t * H_SZ];
    a1 += a[t + 1] * e[(size_t)(t + 1) * H_SZ];
    a2 += a[t + 2] * e[(size_t)(t + 2) * H_SZ];
    a3 += a[t + 3] * e[(size_t)(t + 3) * H_SZ];
  }
  atomicAdd(&ctx[b * H_SZ + h], (a0 + a1) + (a2 + a3));
}

// ---------------------------------------------------------------------------
extern "C" void kernel_launch(void* const* d_in, const int* in_sizes, int n_in,
                              void* d_out, int out_size, void* d_ws, size_t ws_size,
                              hipStream_t stream) {
  const float* dec = (const float*)d_in[0];
  const float* enc = (const float*)d_in[1];
  const float* W1  = (const float*)d_in[2];
  const float* b1  = (const float*)d_in[3];
  const float* W2  = (const float*)d_in[4];
  const float* b2  = (const float*)d_in[5];
  const float* Vv  = (const float*)d_in[6];
  // d_in[7] = bv: constant shift inside softmax -> no effect on outputs.

  const size_t encb_bytes = (size_t)B_SZ * T_SZ * H_SZ * 2;   // 128 MB
  const size_t fast_need  = encb_bytes + (2u << 20) + (128u << 10) + (256u << 10);
  const bool fast = ws_size >= fast_need;

  char* ws = (char*)d_ws;
  unsigned short* encb = nullptr;
  unsigned short* W2t;
  float *qq, *score;
  if (fast) {
    encb  = (unsigned short*)ws;
    W2t   = (unsigned short*)(ws + encb_bytes);
    qq    = (float*)(ws + encb_bytes + (2u << 20));
    score = (float*)(ws + encb_bytes + (2u << 20) + (128u << 10));
  } else {
    W2t   = (unsigned short*)ws;
    qq    = (float*)(ws + (2u << 20));
    score = (float*)(ws + (2u << 20) + (128u << 10));
  }

  float* ctx  = (float*)d_out;                  // [32,1024]
  float* attn = (float*)d_out + B_SZ * H_SZ;    // [32,2048,1]

  hipMemsetAsync(ctx, 0, B_SZ * H_SZ * sizeof(float), stream);
  const int cvtN = fast ? (B_SZ * T_SZ * H_SZ) / (256 * 8) : 0;   // 2048 or 0
  k_prep<<<cvtN + 256 + 512, 256, 0, stream>>>(enc, encb, W2, W2t,
                                               dec, W1, b1, b2, qq, cvtN);
  if (fast)
    k_gemm_score2<<<(B_SZ * T_SZ) / BM2, 512, 0, stream>>>(encb, W2t, qq, Vv, score);
  else
    k_gemm_score_f32<<<(B_SZ * T_SZ) / BM, 256, 0, stream>>>(enc, W2t, qq, Vv, score);
  k_softmax<<<32, 256, 0, stream>>>(score, attn);
  if (fast)
    k_context_bf16<<<dim3(8, 2, 32), 256, 0, stream>>>(encb, attn, ctx);
  else
    k_context_f32<<<dim3(8, 4, 32), 256, 0, stream>>>(enc, attn, ctx);
}